// Round 7
// baseline (1736.060 us; speedup 1.0000x reference)
//
#include <hip/hip_runtime.h>

// Residual VQ via bf16-split MFMA distances + exact-fp32-chain margin rescue.
// B-fragments staged through LDS with async global_load_lds (double-buffered).
// x [B,N,D] fp32, codebooks [Q,C,D] fp32.
// d_out (flat fp32): qout [M*D], indices [M*Q] (as float), losses [Q]
typedef __attribute__((ext_vector_type(8))) short short8;
typedef __attribute__((ext_vector_type(4))) float f32x4;

constexpr int Bq = 8, Nn = 4096, Dd = 256, Qq = 8, Cc = 1024;
constexpr int Mm = Bq * Nn;        // 32768 tokens
constexpr int TOK = 64;            // tokens per block (4 waves x 16)
constexpr int NT = 256;
constexpr int LCAP = 16;           // rescue list capacity per token
constexpr float MARGIN = 0.5f;     // >= 8 sigma of |2-term-mfma - fp32-chain| score error

__device__ inline unsigned short f2bf(float f) {          // fp32 -> bf16 RNE
  unsigned u = __float_as_uint(f);
  unsigned r = (u + 0x7FFFu + ((u >> 16) & 1u)) >> 16;
  return (unsigned short)r;
}
__device__ inline float bf2f(unsigned short h) { return __uint_as_float(((unsigned)h) << 16); }

// ---------------------------------------------------------------------------
// prep: cnorm[q*C+c] = sum_d cb[q][c][d]^2 ; zero loss accumulators
__global__ void prep_kernel(const float* __restrict__ cbs,
                            float* __restrict__ cnorm,
                            float* __restrict__ loss_acc) {
  const int wave = threadIdx.x >> 6;
  const int lane = threadIdx.x & 63;
  const int row  = blockIdx.x * 4 + wave;            // 0 .. Q*C-1
  const float4* r4 = reinterpret_cast<const float4*>(cbs + (size_t)row * Dd);
  const float4 v = r4[lane];
  float s = v.x * v.x + v.y * v.y + v.z * v.z + v.w * v.w;
#pragma unroll
  for (int off = 32; off; off >>= 1) s += __shfl_down(s, off);
  if (lane == 0) cnorm[row] = s;
  if (blockIdx.x == 0 && threadIdx.x < Qq) loss_acc[threadIdx.x] = 0.0f;
}

// ---------------------------------------------------------------------------
// Build frag-major bf16 hi/lo codebook: Bfrag[q][nt][ks][lane] (short8 each) =
// cb[q][ nt*16 + (lane&15) ][ ks*32 + (lane>>4)*8 + j ], j=0..7.
__global__ __launch_bounds__(NT)
void build_bfrag(const float* __restrict__ cbs,
                 short* __restrict__ Bh, short* __restrict__ Bl) {
  const int q    = blockIdx.x >> 6;      // grid = Q*64
  const int nt   = blockIdx.x & 63;
  const int lane = threadIdx.x & 63;
  const int ks0  = threadIdx.x >> 6;     // 0..3
#pragma unroll
  for (int h = 0; h < 2; ++h) {
    const int ks = ks0 + h * 4;
    const int c  = nt * 16 + (lane & 15);
    const int k  = ks * 32 + (lane >> 4) * 8;
    const float* src = cbs + ((size_t)(q * Cc + c)) * Dd + k;
    short8 hi, lo;
#pragma unroll
    for (int j = 0; j < 8; ++j) {
      const float f = src[j];
      const unsigned short hb = f2bf(f);
      hi[j] = (short)hb;
      lo[j] = (short)f2bf(f - bf2f(hb));
    }
    const size_t off = (((size_t)(q * 64 + nt) * 8 + ks) * 64 + lane);
    ((short8*)Bh)[off] = hi;
    ((short8*)Bl)[off] = lo;
  }
}

// ---------------------------------------------------------------------------
// exact fp32-chain score from global residual row (bitwise-identical chain:
// ascending d4, components x,y,z,w, accumulated from 0.0f)
__device__ float exact_score_g(const float4* __restrict__ rv4,
                               const float* __restrict__ cb,
                               const float* __restrict__ cnorm, int cand) {
  const float4* cv = reinterpret_cast<const float4*>(cb + (size_t)cand * Dd);
  float a = 0.0f;
#pragma unroll 1
  for (int d4 = 0; d4 < 64; ++d4) {
    const float4 rv = rv4[d4];
    const float4 c4 = cv[d4];
    a += rv.x * c4.x; a += rv.y * c4.y; a += rv.z * c4.z; a += rv.w * c4.w;
  }
  return cnorm[cand] - 2.0f * a;
}

// ---------------------------------------------------------------------------
// one VQ stage. grid: Mm/TOK = 512 blocks x 256 threads (wave w: tokens w*16..+16)
__global__ __launch_bounds__(NT, 2)
void vq_stage(const float* __restrict__ cb,      // [C][D] fp32 this stage
              const short8* __restrict__ bh,     // frag-major bf16 hi, this stage
              const short8* __restrict__ bl,     // frag-major bf16 lo
              const float* __restrict__ cnorm,   // [C] this stage
              const float* __restrict__ rin,     // [M][D] residual in
              float* __restrict__ rout,          // [M][D] residual out
              float* __restrict__ qout,          // [M][D] accumulated quantized
              float* __restrict__ idx_out,       // [M][Q] indices as float
              float* __restrict__ loss_acc,      // [Q]
              int q) {
  // [dbuf][tile(2)][ks(8)][hl(2)][lane(64)] short8 = 64 KB
  __shared__ short8 bbuf[2][2][8][2][64];
  __shared__ int cnt[TOK];
  __shared__ int list[TOK][LCAP];
  __shared__ int win[TOK];

  const int tid  = threadIdx.x;
  const int lane = tid & 63;
  const int wv   = tid >> 6;
  const int tok0 = blockIdx.x * TOK;

  if (tid < TOK) cnt[tid] = 0;

  // ---- phase A: per-lane A-fragments (bf16 hi of residual) from global.
  short8 ah[8];
  {
    const int tk = wv * 16 + (lane & 15);
    const float* rbase = rin + (size_t)(tok0 + tk) * Dd + (lane >> 4) * 8;
#pragma unroll
    for (int ks = 0; ks < 8; ++ks) {
      const float4 f0 = *reinterpret_cast<const float4*>(rbase + ks * 32);
      const float4 f1 = *reinterpret_cast<const float4*>(rbase + ks * 32 + 4);
      const float v[8] = {f0.x, f0.y, f0.z, f0.w, f1.x, f1.y, f1.z, f1.w};
#pragma unroll
      for (int j = 0; j < 8; ++j) ah[ks][j] = (short)f2bf(v[j]);
    }
  }

  // ---- phase B: 32 groups of 2 N-tiles; B-frags async-staged to LDS (dbuf).
  auto stage_group = [&](int nt0, int db) {
    short8* dst0 = &bbuf[db][0][0][0][0];
#pragma unroll
    for (int i = 0; i < 8; ++i) {
      const int c  = wv * 8 + i;
      const int t  = c >> 4, ks = (c >> 1) & 7, hl = c & 1;
      const short8* src = (hl ? bl : bh) + (((size_t)(nt0 + t) * 8 + ks) * 64 + lane);
      short8* dst = dst0 + ((t * 8 + ks) * 2 + hl) * 64;
      __builtin_amdgcn_global_load_lds(
          (const __attribute__((address_space(1))) void*)src,
          (__attribute__((address_space(3))) void*)dst, 16, 0, 0);
    }
  };

  float runm[4] = {3.4e38f, 3.4e38f, 3.4e38f, 3.4e38f};
  const int col = lane & 15;
  const int g4  = lane >> 4;                     // token rows g4*4 .. g4*4+3

  stage_group(0, 0);
  __syncthreads();                               // drains vmcnt -> buf0 ready

#pragma unroll 1
  for (int g = 0; g < 32; ++g) {
    if (g + 1 < 32) stage_group((g + 1) * 2, (g + 1) & 1);
    const int b = g & 1;

    float cn[2];
#pragma unroll
    for (int j = 0; j < 2; ++j) cn[j] = cnorm[(g * 2 + j) * 16 + col];

    f32x4 acch[2], accl[2];
#pragma unroll
    for (int j = 0; j < 2; ++j) { acch[j] = (f32x4){0.f,0.f,0.f,0.f}; accl[j] = (f32x4){0.f,0.f,0.f,0.f}; }

#pragma unroll
    for (int ks = 0; ks < 8; ++ks) {
      const short8 vh0 = bbuf[b][0][ks][0][lane];
      const short8 vl0 = bbuf[b][0][ks][1][lane];
      const short8 vh1 = bbuf[b][1][ks][0][lane];
      const short8 vl1 = bbuf[b][1][ks][1][lane];
      acch[0] = __builtin_amdgcn_mfma_f32_16x16x32_bf16(ah[ks], vh0, acch[0], 0, 0, 0);
      accl[0] = __builtin_amdgcn_mfma_f32_16x16x32_bf16(ah[ks], vl0, accl[0], 0, 0, 0);
      acch[1] = __builtin_amdgcn_mfma_f32_16x16x32_bf16(ah[ks], vh1, acch[1], 0, 0, 0);
      accl[1] = __builtin_amdgcn_mfma_f32_16x16x32_bf16(ah[ks], vl1, accl[1], 0, 0, 0);
    }

    // bookkeeping: 8 shfl chains (2 tiles x 4 rows), then sequential
    // prefix-min margin collection in ascending tile order (validated).
    float s[2][4], v[2][4];
#pragma unroll
    for (int j = 0; j < 2; ++j)
#pragma unroll
      for (int r = 0; r < 4; ++r) { s[j][r] = cn[j] - 2.0f * (acch[j][r] + accl[j][r]); v[j][r] = s[j][r]; }
#pragma unroll
    for (int m = 1; m < 16; m <<= 1)
#pragma unroll
      for (int j = 0; j < 2; ++j)
#pragma unroll
        for (int r = 0; r < 4; ++r) {
          const float o = __shfl_xor(v[j][r], m);
          v[j][r] = o < v[j][r] ? o : v[j][r];
        }
#pragma unroll
    for (int j = 0; j < 2; ++j) {
#pragma unroll
      for (int r = 0; r < 4; ++r) {
        const float nr = v[j][r] < runm[r] ? v[j][r] : runm[r];
        runm[r] = nr;
        if (s[j][r] <= nr + MARGIN) {
          const int t = wv * 16 + g4 * 4 + r;
          const int pos = atomicAdd(&cnt[t], 1);
          if (pos < LCAP) list[t][pos] = (g * 2 + j) * 16 + col;
        }
      }
    }
    __syncthreads();   // buf[b] consumed by all waves; drains in-flight stage
  }

  // ---- phase C: rescue (one thread per token). cnt==1 -> proven exact winner.
  if (tid < TOK) {
    const int t = tid;
    const float4* rv4 = reinterpret_cast<const float4*>(rin + (size_t)(tok0 + t) * Dd);
    const int c_ = cnt[t];
    int wdx;
    if (c_ == 1) {
      wdx = list[t][0];
    } else if (c_ <= LCAP) {
      float best = 3.4e38f; wdx = 1 << 30;
      for (int it = 0; it < c_; ++it) {
        const int cand = list[t][it];
        const float sc = exact_score_g(rv4, cb, cnorm, cand);
        if (sc < best || (sc == best && cand < wdx)) { best = sc; wdx = cand; }
      }
    } else {            // overflow safety net: full exact scan (never expected)
      float best = 3.4e38f; wdx = 1 << 30;
      for (int cand = 0; cand < Cc; ++cand) {
        const float sc = exact_score_g(rv4, cb, cnorm, cand);
        if (sc < best) { best = sc; wdx = cand; }
      }
    }
    win[t] = wdx;
    idx_out[(size_t)(tok0 + t) * Qq + q] = (float)wdx;
  }
  __syncthreads();

  // ---- phase D: epilogue (bitwise-validated elementwise sequence)
  //   e = q - r; q_st = r + e; r_new = r - q_st; qout += q_st; loss += e^2
  float lsum = 0.0f;
  {
    const float4* cb4 = reinterpret_cast<const float4*>(cb);
    const float4* rinp = reinterpret_cast<const float4*>(rin + (size_t)tok0 * Dd);
    float4* routp = reinterpret_cast<float4*>(rout + (size_t)tok0 * Dd);
    float4* qoutp = reinterpret_cast<float4*>(qout + (size_t)tok0 * Dd);
#pragma unroll
    for (int k = 0; k < 16; ++k) {
      const int j = tid + k * NT;
      const int tk = j >> 6, d4 = j & 63;
      const int widx = win[tk];
      const float4 cv = cb4[(size_t)widx * 64 + d4];
      const float4 rv = rinp[j];
      const float ex = cv.x - rv.x, ey = cv.y - rv.y, ez = cv.z - rv.z, ew = cv.w - rv.w;
      const float qsx = rv.x + ex, qsy = rv.y + ey, qsz = rv.z + ez, qsw = rv.w + ew;
      lsum += ex * ex + ey * ey + ez * ez + ew * ew;
      routp[j] = make_float4(rv.x - qsx, rv.y - qsy, rv.z - qsz, rv.w - qsw);
      float4 qo;
      if (q == 0) {
        qo = make_float4(qsx, qsy, qsz, qsw);
      } else {
        const float4 old = qoutp[j];
        qo = make_float4(old.x + qsx, old.y + qsy, old.z + qsz, old.w + qsw);
      }
      qoutp[j] = qo;
    }
  }
#pragma unroll
  for (int s = 32; s; s >>= 1) lsum += __shfl_xor(lsum, s);
  if (lane == 0) atomicAdd(&loss_acc[q], lsum);
}

// ---------------------------------------------------------------------------
__global__ void finalize_losses(const float* __restrict__ loss_acc,
                                float* __restrict__ loss_out) {
  if (threadIdx.x < Qq) loss_out[threadIdx.x] = loss_acc[threadIdx.x] * (1.0f / (float)(Mm * Dd));
}

extern "C" void kernel_launch(void* const* d_in, const int* in_sizes, int n_in,
                              void* d_out, int out_size, void* d_ws, size_t ws_size,
                              hipStream_t stream) {
  const float* x   = (const float*)d_in[0];   // [B,N,D]
  const float* cbs = (const float*)d_in[1];   // [Q,C,D]
  float* out      = (float*)d_out;
  float* qout     = out;                               // M*D
  float* idx_out  = out + (size_t)Mm * Dd;             // M*Q
  float* loss_out = idx_out + (size_t)Mm * Qq;         // Q

  char* w = (char*)d_ws;
  float* residual = (float*)w;                                  // 32 MB
  short* Bh       = (short*)(w + (size_t)33554432);             // 4 MB
  short* Bl       = (short*)(w + (size_t)37748736);             // 4 MB
  float* cnorm    = (float*)(w + (size_t)41943040);             // 32 KB
  float* loss_acc = (float*)(w + (size_t)41975808);             // 256 B

  prep_kernel<<<(Qq * Cc) / 4, NT, 0, stream>>>(cbs, cnorm, loss_acc);
  build_bfrag<<<Qq * 64, NT, 0, stream>>>(cbs, Bh, Bl);

  for (int q = 0; q < Qq; ++q) {
    const float* rin = (q == 0) ? x : residual;
    vq_stage<<<Mm / TOK, NT, 0, stream>>>(
        cbs + (size_t)q * Cc * Dd,
        (const short8*)Bh + (size_t)q * 32768,
        (const short8*)Bl + (size_t)q * 32768,
        cnorm + (size_t)q * Cc,
        rin, residual, qout, idx_out, loss_acc, q);
  }

  finalize_losses<<<1, 64, 0, stream>>>(loss_acc, loss_out);
}

// Round 8
// 1067.977 us; speedup vs baseline: 1.6256x; 1.6256x over previous
//
#include <hip/hip_runtime.h>

// Residual VQ via bf16-split MFMA distances + exact-fp32-chain margin rescue.
// B-fragments staged through LDS with async global_load_lds (double-buffered);
// residual tile re-staged into the same LDS after the matmul for rescue+epilogue.
// x [B,N,D] fp32, codebooks [Q,C,D] fp32.
// d_out (flat fp32): qout [M*D], indices [M*Q] (as float), losses [Q]
typedef __attribute__((ext_vector_type(8))) short short8;
typedef __attribute__((ext_vector_type(4))) float f32x4;

constexpr int Bq = 8, Nn = 4096, Dd = 256, Qq = 8, Cc = 1024;
constexpr int Mm = Bq * Nn;        // 32768 tokens
constexpr int TOK = 64;            // tokens per block (4 waves x 16)
constexpr int NT = 256;
constexpr int LCAP = 16;           // rescue list capacity per token
constexpr float MARGIN = 0.5f;     // >= 8 sigma of |2-term-mfma - fp32-chain| score error

__device__ inline unsigned short f2bf(float f) {          // fp32 -> bf16 RNE
  unsigned u = __float_as_uint(f);
  unsigned r = (u + 0x7FFFu + ((u >> 16) & 1u)) >> 16;
  return (unsigned short)r;
}
__device__ inline float bf2f(unsigned short h) { return __uint_as_float(((unsigned)h) << 16); }

// ---------------------------------------------------------------------------
// prep: cnorm[q*C+c] = sum_d cb[q][c][d]^2 ; zero loss accumulators
__global__ void prep_kernel(const float* __restrict__ cbs,
                            float* __restrict__ cnorm,
                            float* __restrict__ loss_acc) {
  const int wave = threadIdx.x >> 6;
  const int lane = threadIdx.x & 63;
  const int row  = blockIdx.x * 4 + wave;            // 0 .. Q*C-1
  const float4* r4 = reinterpret_cast<const float4*>(cbs + (size_t)row * Dd);
  const float4 v = r4[lane];
  float s = v.x * v.x + v.y * v.y + v.z * v.z + v.w * v.w;
#pragma unroll
  for (int off = 32; off; off >>= 1) s += __shfl_down(s, off);
  if (lane == 0) cnorm[row] = s;
  if (blockIdx.x == 0 && threadIdx.x < Qq) loss_acc[threadIdx.x] = 0.0f;
}

// ---------------------------------------------------------------------------
// Build frag-major bf16 hi/lo codebook: Bfrag[q][nt][ks][lane] (short8 each) =
// cb[q][ nt*16 + (lane&15) ][ ks*32 + (lane>>4)*8 + j ], j=0..7.
__global__ __launch_bounds__(NT)
void build_bfrag(const float* __restrict__ cbs,
                 short* __restrict__ Bh, short* __restrict__ Bl) {
  const int q    = blockIdx.x >> 6;      // grid = Q*64
  const int nt   = blockIdx.x & 63;
  const int lane = threadIdx.x & 63;
  const int ks0  = threadIdx.x >> 6;     // 0..3
#pragma unroll
  for (int h = 0; h < 2; ++h) {
    const int ks = ks0 + h * 4;
    const int c  = nt * 16 + (lane & 15);
    const int k  = ks * 32 + (lane >> 4) * 8;
    const float* src = cbs + ((size_t)(q * Cc + c)) * Dd + k;
    short8 hi, lo;
#pragma unroll
    for (int j = 0; j < 8; ++j) {
      const float f = src[j];
      const unsigned short hb = f2bf(f);
      hi[j] = (short)hb;
      lo[j] = (short)f2bf(f - bf2f(hb));
    }
    const size_t off = (((size_t)(q * 64 + nt) * 8 + ks) * 64 + lane);
    ((short8*)Bh)[off] = hi;
    ((short8*)Bl)[off] = lo;
  }
}

// ---------------------------------------------------------------------------
// exact fp32-chain score from the swizzled LDS tile. The accumulation chain
// (ascending d4, components x,y,z,w, from 0.0f) is bitwise-identical to the
// validated rounds-1..7 chain; unrolling only batches loads, fp order is
// preserved (no fast-math reassociation).
__device__ float exact_score_lds(const float4* __restrict__ tile, int t, int sw,
                                 const float* __restrict__ cb,
                                 const float* __restrict__ cnorm, int cand) {
  const float4* cv = reinterpret_cast<const float4*>(cb + (size_t)cand * Dd);
  float a = 0.0f;
#pragma unroll 8
  for (int d4 = 0; d4 < 64; ++d4) {
    const float4 rv = tile[(t * 64 + d4) ^ sw];
    const float4 c4 = cv[d4];
    a += rv.x * c4.x; a += rv.y * c4.y; a += rv.z * c4.z; a += rv.w * c4.w;
  }
  return cnorm[cand] - 2.0f * a;
}

// ---------------------------------------------------------------------------
// one VQ stage. grid: Mm/TOK = 512 blocks x 256 threads (wave w: tokens w*16..+16)
__global__ __launch_bounds__(NT, 2)
void vq_stage(const float* __restrict__ cb,      // [C][D] fp32 this stage
              const short8* __restrict__ bh,     // frag-major bf16 hi, this stage
              const short8* __restrict__ bl,     // frag-major bf16 lo
              const float* __restrict__ cnorm,   // [C] this stage
              const float* __restrict__ rin,     // [M][D] residual in
              float* __restrict__ rout,          // [M][D] residual out
              float* __restrict__ qout,          // [M][D] accumulated quantized
              float* __restrict__ idx_out,       // [M][Q] indices as float
              float* __restrict__ loss_acc,      // [Q]
              int q) {
  // [dbuf][tile(2)][ks(8)][hl(2)][lane(64)] short8 = 64 KB; reused as the
  // fp32 residual tile (TOK*64 float4 = 64 KB) after phase B.
  __shared__ short8 bbuf[2][2][8][2][64];
  __shared__ int cnt[TOK];
  __shared__ int list[TOK][LCAP];
  __shared__ int win[TOK];

  const int tid  = threadIdx.x;
  const int lane = tid & 63;
  const int wv   = tid >> 6;
  const int tok0 = blockIdx.x * TOK;

  if (tid < TOK) cnt[tid] = 0;

  // ---- phase A: per-lane A-fragments (bf16 hi of residual) from global.
  short8 ah[8];
  {
    const int tk = wv * 16 + (lane & 15);
    const float* rbase = rin + (size_t)(tok0 + tk) * Dd + (lane >> 4) * 8;
#pragma unroll
    for (int ks = 0; ks < 8; ++ks) {
      const float4 f0 = *reinterpret_cast<const float4*>(rbase + ks * 32);
      const float4 f1 = *reinterpret_cast<const float4*>(rbase + ks * 32 + 4);
      const float v[8] = {f0.x, f0.y, f0.z, f0.w, f1.x, f1.y, f1.z, f1.w};
#pragma unroll
      for (int j = 0; j < 8; ++j) ah[ks][j] = (short)f2bf(v[j]);
    }
  }

  // ---- phase B: 32 groups of 2 N-tiles; B-frags async-staged to LDS (dbuf).
  auto stage_group = [&](int nt0, int db) {
    short8* dst0 = &bbuf[db][0][0][0][0];
#pragma unroll
    for (int i = 0; i < 8; ++i) {
      const int c  = wv * 8 + i;
      const int t  = c >> 4, ks = (c >> 1) & 7, hl = c & 1;
      const short8* src = (hl ? bl : bh) + (((size_t)(nt0 + t) * 8 + ks) * 64 + lane);
      short8* dst = dst0 + ((t * 8 + ks) * 2 + hl) * 64;
      __builtin_amdgcn_global_load_lds(
          (const __attribute__((address_space(1))) void*)src,
          (__attribute__((address_space(3))) void*)dst, 16, 0, 0);
    }
  };

  float runm[4] = {3.4e38f, 3.4e38f, 3.4e38f, 3.4e38f};
  const int col = lane & 15;
  const int g4  = lane >> 4;                     // token rows g4*4 .. g4*4+3

  stage_group(0, 0);
  __syncthreads();                               // drains vmcnt -> buf0 ready

#pragma unroll 1
  for (int g = 0; g < 32; ++g) {
    if (g + 1 < 32) stage_group((g + 1) * 2, (g + 1) & 1);
    const int b = g & 1;

    float cn[2];
#pragma unroll
    for (int j = 0; j < 2; ++j) cn[j] = cnorm[(g * 2 + j) * 16 + col];

    f32x4 acch[2], accl[2];
#pragma unroll
    for (int j = 0; j < 2; ++j) { acch[j] = (f32x4){0.f,0.f,0.f,0.f}; accl[j] = (f32x4){0.f,0.f,0.f,0.f}; }

#pragma unroll
    for (int ks = 0; ks < 8; ++ks) {
      const short8 vh0 = bbuf[b][0][ks][0][lane];
      const short8 vl0 = bbuf[b][0][ks][1][lane];
      const short8 vh1 = bbuf[b][1][ks][0][lane];
      const short8 vl1 = bbuf[b][1][ks][1][lane];
      acch[0] = __builtin_amdgcn_mfma_f32_16x16x32_bf16(ah[ks], vh0, acch[0], 0, 0, 0);
      accl[0] = __builtin_amdgcn_mfma_f32_16x16x32_bf16(ah[ks], vl0, accl[0], 0, 0, 0);
      acch[1] = __builtin_amdgcn_mfma_f32_16x16x32_bf16(ah[ks], vh1, acch[1], 0, 0, 0);
      accl[1] = __builtin_amdgcn_mfma_f32_16x16x32_bf16(ah[ks], vl1, accl[1], 0, 0, 0);
    }

    // bookkeeping: 8 shfl chains (2 tiles x 4 rows), then sequential
    // prefix-min margin collection in ascending tile order (validated).
    float s[2][4], v[2][4];
#pragma unroll
    for (int j = 0; j < 2; ++j)
#pragma unroll
      for (int r = 0; r < 4; ++r) { s[j][r] = cn[j] - 2.0f * (acch[j][r] + accl[j][r]); v[j][r] = s[j][r]; }
#pragma unroll
    for (int m = 1; m < 16; m <<= 1)
#pragma unroll
      for (int j = 0; j < 2; ++j)
#pragma unroll
        for (int r = 0; r < 4; ++r) {
          const float o = __shfl_xor(v[j][r], m);
          v[j][r] = o < v[j][r] ? o : v[j][r];
        }
#pragma unroll
    for (int j = 0; j < 2; ++j) {
#pragma unroll
      for (int r = 0; r < 4; ++r) {
        const float nr = v[j][r] < runm[r] ? v[j][r] : runm[r];
        runm[r] = nr;
        if (s[j][r] <= nr + MARGIN) {
          const int t = wv * 16 + g4 * 4 + r;
          const int pos = atomicAdd(&cnt[t], 1);
          if (pos < LCAP) list[t][pos] = (g * 2 + j) * 16 + col;
        }
      }
    }
    __syncthreads();   // buf[b] consumed by all waves; drains in-flight stage
  }

  // ---- phase B2: bbuf is free now — re-stage fp32 residual tile into LDS
  // (round-5 swizzle) for rescue + epilogue.
  float4* tile = reinterpret_cast<float4*>(&bbuf[0][0][0][0][0]);
  {
    const float4* src = reinterpret_cast<const float4*>(rin + (size_t)tok0 * Dd);
#pragma unroll
    for (int k = 0; k < 16; ++k) {
      const int j = tid + k * NT;
      const int tk = j >> 6, d4 = j & 63;
      tile[(tk * 64 + d4) ^ (tk & 7)] = src[j];
    }
  }
  __syncthreads();

  // ---- phase C: parallel rescue — 4 threads per token, candidate-sliced.
  // Per-candidate score = unchanged sequential fp32 chain (bitwise-identical);
  // 4-lane min-reduce with lowest-index tie-break is order-equivalent to the
  // validated sequential scan.
  {
    const int t    = tid >> 2;
    const int slot = tid & 3;
    const int sw   = t & 7;
    const int c_   = cnt[t];
    float best = 3.4e38f;
    int   wdx  = 1 << 30;
    if (c_ == 1) {
      wdx = list[t][0];
      best = 0.0f;                         // uniform across the 4 lanes
    } else if (c_ <= LCAP) {
      for (int it = slot; it < c_; it += 4) {
        const int cand = list[t][it];
        const float sc = exact_score_lds(tile, t, sw, cb, cnorm, cand);
        if (sc < best || (sc == best && cand < wdx)) { best = sc; wdx = cand; }
      }
    } else {          // overflow safety net: full exact scan, candidate-sliced
      for (int cand = slot; cand < Cc; cand += 4) {
        const float sc = exact_score_lds(tile, t, sw, cb, cnorm, cand);
        if (sc < best || (sc == best && cand < wdx)) { best = sc; wdx = cand; }
      }
    }
    // butterfly over the aligned 4-lane group (stays in-group for xor 1,2)
#pragma unroll
    for (int m = 1; m < 4; m <<= 1) {
      const float ov = __shfl_xor(best, m);
      const int   oi = __shfl_xor(wdx, m);
      if (ov < best || (ov == best && oi < wdx)) { best = ov; wdx = oi; }
    }
    if (slot == 0) {
      win[t] = wdx;
      idx_out[(size_t)(tok0 + t) * Qq + q] = (float)wdx;
    }
  }
  __syncthreads();

  // ---- phase D: epilogue from LDS tile (bitwise-validated elementwise chain)
  //   e = q - r; q_st = r + e; r_new = r - q_st; qout += q_st; loss += e^2
  float lsum = 0.0f;
  {
    const float4* cb4 = reinterpret_cast<const float4*>(cb);
    float4* routp = reinterpret_cast<float4*>(rout + (size_t)tok0 * Dd);
    float4* qoutp = reinterpret_cast<float4*>(qout + (size_t)tok0 * Dd);
#pragma unroll
    for (int k = 0; k < 16; ++k) {
      const int j = tid + k * NT;
      const int tk = j >> 6, d4 = j & 63;
      const int widx = win[tk];
      const float4 cv = cb4[(size_t)widx * 64 + d4];
      const float4 rv = tile[(tk * 64 + d4) ^ (tk & 7)];
      const float ex = cv.x - rv.x, ey = cv.y - rv.y, ez = cv.z - rv.z, ew = cv.w - rv.w;
      const float qsx = rv.x + ex, qsy = rv.y + ey, qsz = rv.z + ez, qsw = rv.w + ew;
      lsum += ex * ex + ey * ey + ez * ez + ew * ew;
      routp[j] = make_float4(rv.x - qsx, rv.y - qsy, rv.z - qsz, rv.w - qsw);
      float4 qo;
      if (q == 0) {
        qo = make_float4(qsx, qsy, qsz, qsw);
      } else {
        const float4 old = qoutp[j];
        qo = make_float4(old.x + qsx, old.y + qsy, old.z + qsz, old.w + qsw);
      }
      qoutp[j] = qo;
    }
  }
#pragma unroll
  for (int s = 32; s; s >>= 1) lsum += __shfl_xor(lsum, s);
  if (lane == 0) atomicAdd(&loss_acc[q], lsum);
}

// ---------------------------------------------------------------------------
__global__ void finalize_losses(const float* __restrict__ loss_acc,
                                float* __restrict__ loss_out) {
  if (threadIdx.x < Qq) loss_out[threadIdx.x] = loss_acc[threadIdx.x] * (1.0f / (float)(Mm * Dd));
}

extern "C" void kernel_launch(void* const* d_in, const int* in_sizes, int n_in,
                              void* d_out, int out_size, void* d_ws, size_t ws_size,
                              hipStream_t stream) {
  const float* x   = (const float*)d_in[0];   // [B,N,D]
  const float* cbs = (const float*)d_in[1];   // [Q,C,D]
  float* out      = (float*)d_out;
  float* qout     = out;                               // M*D
  float* idx_out  = out + (size_t)Mm * Dd;             // M*Q
  float* loss_out = idx_out + (size_t)Mm * Qq;         // Q

  char* w = (char*)d_ws;
  float* residual = (float*)w;                                  // 32 MB
  short* Bh       = (short*)(w + (size_t)33554432);             // 4 MB
  short* Bl       = (short*)(w + (size_t)37748736);             // 4 MB
  float* cnorm    = (float*)(w + (size_t)41943040);             // 32 KB
  float* loss_acc = (float*)(w + (size_t)41975808);             // 256 B

  prep_kernel<<<(Qq * Cc) / 4, NT, 0, stream>>>(cbs, cnorm, loss_acc);
  build_bfrag<<<Qq * 64, NT, 0, stream>>>(cbs, Bh, Bl);

  for (int q = 0; q < Qq; ++q) {
    const float* rin = (q == 0) ? x : residual;
    vq_stage<<<Mm / TOK, NT, 0, stream>>>(
        cbs + (size_t)q * Cc * Dd,
        (const short8*)Bh + (size_t)q * 32768,
        (const short8*)Bl + (size_t)q * 32768,
        cnorm + (size_t)q * Cc,
        rin, residual, qout, idx_out, loss_acc, q);
  }

  finalize_losses<<<1, 64, 0, stream>>>(loss_acc, loss_out);
}